// Round 13
// baseline (181.282 us; speedup 1.0000x reference)
//
#include <hip/hip_runtime.h>
#include <hip/hip_bf16.h>

typedef unsigned short ushort_t;
using floatx4 = __attribute__((__ext_vector_type__(4))) float;
using bf16x8  = __attribute__((__ext_vector_type__(8))) __bf16;
using ushort4v = __attribute__((__ext_vector_type__(4))) ushort_t;

// packed f32x2 -> bf16x2 (v_cvt_pk_bf16_f32); memcpy because __hip_bfloat162
// is not trivially copyable
__device__ __forceinline__ unsigned int pkbf(float a, float b) {
  __hip_bfloat162 h = __float22bfloat162_rn(make_float2(a, b));
  unsigned int u;
  __builtin_memcpy(&u, &h, 4);
  return u;
}

// async global->LDS, 16B per lane; lds dest is wave-uniform base (HW adds lane*16)
__device__ __forceinline__ void gl2lds16(const ushort_t* g, ushort_t* l) {
  __builtin_amdgcn_global_load_lds(
      (const __attribute__((address_space(1))) unsigned int*)g,
      (__attribute__((address_space(3))) unsigned int*)l, 16, 0, 0);
}

// ---------------- merged cast fp32 -> bf16 of x, qkv_w, proj_w + cos/sin table ----------------
__global__ void cast_all(const float* __restrict__ x, const float* __restrict__ qw,
                         const float* __restrict__ pw, ushort_t* __restrict__ ob,
                         const float* __restrict__ pos, float* __restrict__ cs) {
  const int T1 = 4096 * 1024, T2 = T1 + 3072 * 1024, T3 = T2 + 1024 * 1024;
  const int tid = blockIdx.x * blockDim.x + threadIdx.x;
  if (tid < 65536) {              // 2048 tokens x 32 angles
    const float a = pos[tid];
    cs[2 * tid]     = __cosf(a);
    cs[2 * tid + 1] = __sinf(a);
  }
  const int i = tid * 4;
  if (i < T3) {
    const float* src = (i < T1) ? (x + i) : (i < T2) ? (qw + (i - T1)) : (pw + (i - T2));
    float4 v = *reinterpret_cast<const float4*>(src);
    uint2 o = make_uint2(pkbf(v.x, v.y), pkbf(v.z, v.w));
    *reinterpret_cast<uint2*>(&ob[i]) = o;
  }
}

// ---------------- QKV GEMM v3: 8-wave blocks, 32x64 per wave + fused epilogue ----------------
// 512 threads, 8 waves: wave w owns m-rows (w>>1)*32.., n-cols (w&1)*64.. (one full head).
// grid (mtile=x 32, ntile=y 24): id%8 pins A-tiles per XCD. LDS 32KB swizzled; the
// per-wave 4KB epilogue tiles alias sA|sB after the K-loop.
__global__ __launch_bounds__(512)
void gemm_qkv_fused(const ushort_t* __restrict__ A, const ushort_t* __restrict__ B,
                    const float* __restrict__ cs,
                    const float* __restrict__ qnw, const float* __restrict__ knw,
                    ushort_t* __restrict__ qr, ushort_t* __restrict__ kr,
                    ushort_t* __restrict__ vt) {
  const int K = 1024;
  __shared__ __align__(16) ushort_t smem[16384];   // 32KB: sA(16K) | sB(16K), aliased by sE
  ushort_t* sA = smem;
  ushort_t* sB = smem + 8192;
  const int m0 = blockIdx.x * 128, n0 = blockIdx.y * 128;
  const int tid = threadIdx.x;
  const int lane = tid & 63, w = tid >> 6;          // w in [0,8)
  const int wm = (w >> 1) * 32;
  const int grp = lane >> 4, l16 = lane & 15;
  const int r8 = lane >> 3;
  const int c8 = ((lane & 7) ^ r8) * 8;
  floatx4 acc[2][4] = {};
  for (int k0 = 0; k0 < K; k0 += 64) {
    __syncthreads();
#pragma unroll
    for (int i = 0; i < 2; i++) {
      const int j = w * 2 + i;                      // chunk 0..15 (8 rows x 128B)
      gl2lds16(&A[(size_t)(m0 + j * 8 + r8) * K + k0 + c8], &sA[j * 512]);
      gl2lds16(&B[(size_t)(n0 + j * 8 + r8) * K + k0 + c8], &sB[j * 512]);
    }
    __syncthreads();
#pragma unroll
    for (int kk = 0; kk < 2; kk++) {
      bf16x8 af[2], bfr[4];
#pragma unroll
      for (int i = 0; i < 2; i++) {
        const int ra = wm + i * 16 + l16;
        af[i] = *reinterpret_cast<const bf16x8*>(
            &sA[ra * 64 + (((kk * 4 + grp) ^ (ra & 7)) << 3)]);
      }
#pragma unroll
      for (int j = 0; j < 4; j++) {
        const int rb = (w & 1) * 64 + j * 16 + l16;
        bfr[j] = *reinterpret_cast<const bf16x8*>(
            &sB[rb * 64 + (((kk * 4 + grp) ^ (rb & 7)) << 3)]);
      }
#pragma unroll
      for (int i = 0; i < 2; i++)
#pragma unroll
        for (int j = 0; j < 4; j++)
          acc[i][j] = __builtin_amdgcn_mfma_f32_16x16x32_bf16(af[i], bfr[j], acc[i][j], 0, 0, 0);
    }
  }
  __syncthreads();                 // all K-loop LDS reads done before epilogue overwrites
  // ---- fused epilogue: per-wave 4KB tile at smem + w*4KB ----
  ushort_t* sE = smem + w * 2048;
  const int region = n0 >> 10;                 // 0=q,1=k,2=v
  const int h = ((n0 & 1023) >> 6) + (w & 1);  // head this wave owns
  const int tbase = m0 + wm;                   // 32-aligned token base
  const int bb = tbase >> 11;
  const int q = lane & 7;
  const int lr = lane >> 3;

  if (region < 2) {
    float* sEf = (float*)sE;                   // 16 tokens x 64 dims fp32 (4KB)
    const float* nwp = (region == 0) ? qnw : knw;
    const float qmul = (region == 0) ? 0.125f * 1.44269504088896340736f : 1.0f;
    float wgt[8];
    *(float4*)&wgt[0] = *(const float4*)&nwp[q * 8];
    *(float4*)&wgt[4] = *(const float4*)&nwp[q * 8 + 4];
#pragma unroll
    for (int p = 0; p < 2; p++) {              // 2 passes x 16 tokens
      __builtin_amdgcn_s_waitcnt(0);
      // phase A: dump fp32 [t2][d], 16B-chunk XOR swizzle by t2
#pragma unroll
      for (int rr = 0; rr < 4; rr++) {
        const int t2 = grp * 4 + rr;
#pragma unroll
        for (int j = 0; j < 4; j++) {
          const int cd = (j * 4 + (l16 >> 2)) ^ t2;
          sEf[t2 * 64 + cd * 4 + (l16 & 3)] = acc[p][j][rr];
        }
      }
      __builtin_amdgcn_s_waitcnt(0);
      // phase B: 8 lanes per token; lane handles dims [8q, 8q+8)
#pragma unroll
      for (int tg = 0; tg < 2; tg++) {
        const int t2 = tg * 8 + lr;
        const int n = (tbase + p * 16 + t2) & 2047;
        float v0[8];
        const int ck1 = (2 * q) ^ t2, ck2 = (2 * q + 1) ^ t2;
        *(float4*)&v0[0] = *(const float4*)&sEf[t2 * 64 + ck1 * 4];
        *(float4*)&v0[4] = *(const float4*)&sEf[t2 * 64 + ck2 * 4];
        float ss = 0.f;
#pragma unroll
        for (int e = 0; e < 8; e++) ss += v0[e] * v0[e];
        ss += __shfl_xor(ss, 1); ss += __shfl_xor(ss, 2); ss += __shfl_xor(ss, 4);
        const float rn = rsqrtf(ss * (1.0f / 64.0f) + 1e-6f);
        float4 c01 = *(const float4*)&cs[(n * 32 + q * 4) * 2];
        float4 c23 = *(const float4*)&cs[(n * 32 + q * 4) * 2 + 4];
        float ccv[4] = {c01.x, c01.z, c23.x, c23.z};
        float snv[4] = {c01.y, c01.w, c23.y, c23.w};
        union { unsigned int u32[4]; uint4 v4; } ov;
#pragma unroll
        for (int pp = 0; pp < 4; pp++) {
          const float cc = ccv[pp], sn = snv[pp];
          const float xr = v0[2 * pp] * rn * wgt[2 * pp];
          const float xi = v0[2 * pp + 1] * rn * wgt[2 * pp + 1];
          ov.u32[pp] = pkbf((xr * cc - xi * sn) * qmul, (xr * sn + xi * cc) * qmul);
        }
        const size_t rowb = ((size_t)(bb * 16 + h) * 2048 + n) * 64;
        if (region == 0)
          *reinterpret_cast<uint4*>(&qr[rowb + q * 8]) = ov.v4;
        else
          *reinterpret_cast<uint4*>(&kr[rowb + (q ^ (n & 7)) * 8]) = ov.v4;
      }
    }
  } else {
    // v region: per-wave [d][32-token] bf16 tile (4KB), rr-quads as b64,
    // 8B-chunk swizzle by d&7. Wave covers half a 64-key window (contiguous
    // permuted half: token t2 -> lidx = grp*8 + i*4 + rr).
    const int nw_ = tbase & 2047;
    const int n64 = nw_ & ~63;
    const int hw = (nw_ >> 5) & 1;             // which half of the window
#pragma unroll
    for (int i = 0; i < 2; i++)
#pragma unroll
      for (int j = 0; j < 4; j++) {
        const int d = j * 16 + l16;
        const int ct = (grp * 2 + i) ^ (d & 7);
        uint2 pk = make_uint2(pkbf(acc[i][j][0], acc[i][j][1]),
                              pkbf(acc[i][j][2], acc[i][j][3]));
        *reinterpret_cast<uint2*>(&sE[d * 32 + ct * 4]) = pk;
      }
    __builtin_amdgcn_s_waitcnt(0);
    // phase B: lane -> (d = dd*16 + lane>>2, lc = lane&3): one 16B granule
    const int lc = lane & 3;
#pragma unroll
    for (int dd = 0; dd < 4; dd++) {
      const int d = dd * 16 + (lane >> 2);
      union { ushort4v hh[2]; uint4 v4; } ob;
      ob.hh[0] = *reinterpret_cast<const ushort4v*>(&sE[d * 32 + (((2 * lc) ^ (d & 7)) * 4)]);
      ob.hh[1] = *reinterpret_cast<const ushort4v*>(&sE[d * 32 + (((2 * lc + 1) ^ (d & 7)) * 4)]);
      *reinterpret_cast<uint4*>(
          &vt[((size_t)(bb * 16 + h) * 64 + d) * 2048 + n64 + (((hw * 4 + lc) ^ (d & 7)) * 8)]) = ob.v4;
    }
  }
}

// ---------------- Flash attention v7: 64-key tiles, 32KB LDS -> 4 blocks/CU = 32 waves/CU ----
// grid (bh=x 32, qtile=y 16), block 512 = 8 waves x 16 q-rows. XCD-pinned bh.
// VGPR ~64 keeps 8 waves/SIMD; LDS 32KB allows 4 blocks/CU -> max occupancy, so the
// per-iter barrier+vmcnt drains overlap with 3 co-resident blocks' compute.
// No running max: ||q||=||k||=8 after RMSNorm => |score*log2e*scale| <= 11.6, exp2-safe.
__global__ __launch_bounds__(512)
void flash_attn(const ushort_t* __restrict__ qr, const ushort_t* __restrict__ kr,
                const ushort_t* __restrict__ vt, ushort_t* __restrict__ aout) {
  const int bh = blockIdx.x;
  const int w = threadIdx.x >> 6, lane = threadIdx.x & 63;
  const int grp = lane >> 4, l16 = lane & 15;
  const int sw = l16 & 7;
  const int q0 = blockIdx.y * 128 + w * 16;   // 16 q-rows per wave
  const size_t hb = (size_t)bh * 2048 * 64;

  __shared__ ushort_t sK[2][64 * 64];   // [key][d-swizzled], 8KB each
  __shared__ ushort_t sV[2][64 * 64];   // [d][64-key window permuted+swizzled], 8KB each

  const ushort_t* qp = &qr[hb + (size_t)(q0 + l16) * 64 + grp * 8];
  const bf16x8 qa0 = *reinterpret_cast<const bf16x8*>(qp);
  const bf16x8 qa1 = *reinterpret_cast<const bf16x8*>(qp + 32);

  floatx4 o[4] = {};
  floatx4 ol = {};        // ones-row accumulator: every reg = Sigma p for this lane's q

  union { ushort_t u[8]; bf16x8 v; } onef;
#pragma unroll
  for (int e = 0; e < 8; e++) onef.u[e] = 0x3F80;   // bf16 1.0

  auto stage = [&](int buf, int k0) {
    // K tile 64x64: 8 chunks of 1KB (8 key-rows each); wave w stages chunk w
    gl2lds16(&kr[hb + (size_t)k0 * 64 + w * 512 + lane * 8], &sK[buf][w * 512]);
    // V tile 64 d-rows x 128B window; wave w stages d-rows w*8..w*8+7
    gl2lds16(&vt[((size_t)bh * 64 + w * 8 + (lane >> 3)) * 2048 + k0 + (lane & 7) * 8],
             &sV[buf][w * 512]);
  };

  stage(0, 0);
  const int g0 = (grp ^ sw) * 8;
  for (int it = 0; it < 32; it++) {
    const int cur = it & 1;
    __syncthreads();
    if (it + 1 < 32) stage(1 - cur, (it + 1) * 64);
    const ushort_t* kb = &sK[cur][0];
    const ushort_t* vb = &sV[cur][0];
    floatx4 s[4];
#pragma unroll
    for (int nt = 0; nt < 4; nt++) {
      const ushort_t* kp = kb + (nt * 16 + l16) * 64;
      bf16x8 kf0 = *reinterpret_cast<const bf16x8*>(kp + g0);
      bf16x8 kf1 = *reinterpret_cast<const bf16x8*>(kp + (g0 ^ 32));
      floatx4 acc = {};
      acc = __builtin_amdgcn_mfma_f32_16x16x32_bf16(kf0, qa0, acc, 0, 0, 0);
      acc = __builtin_amdgcn_mfma_f32_16x16x32_bf16(kf1, qa1, acc, 0, 0, 0);
      s[nt] = acc;
    }
    float p[4][4];
#pragma unroll
    for (int nt = 0; nt < 4; nt++)
#pragma unroll
      for (int r = 0; r < 4; r++)
        p[nt][r] = __builtin_amdgcn_exp2f(s[nt][r]);
    union { unsigned int u32[4]; bf16x8 v; } pf[2];
#pragma unroll
    for (int c = 0; c < 2; c++) {
      pf[c].u32[0] = pkbf(p[2 * c][0], p[2 * c][1]);
      pf[c].u32[1] = pkbf(p[2 * c][2], p[2 * c][3]);
      pf[c].u32[2] = pkbf(p[2 * c + 1][0], p[2 * c + 1][1]);
      pf[c].u32[3] = pkbf(p[2 * c + 1][2], p[2 * c + 1][3]);
    }
#pragma unroll
    for (int c = 0; c < 2; c++) {
      ol = __builtin_amdgcn_mfma_f32_16x16x32_bf16(onef.v, pf[c].v, ol, 0, 0, 0);
#pragma unroll
      for (int dt = 0; dt < 4; dt++) {
        const bf16x8 vv = *reinterpret_cast<const bf16x8*>(
            vb + (dt * 16 + l16) * 64 + (((c * 4 + grp) ^ sw) << 3));
        o[dt] = __builtin_amdgcn_mfma_f32_16x16x32_bf16(vv, pf[c].v, o[dt], 0, 0, 0);
      }
    }
  }
  const int b = bh >> 4, h = bh & 15;
  const float rl = 1.0f / ol[0];
  const size_t orow = (size_t)(b * 2048 + q0 + l16) * 1024 + h * 64;
#pragma unroll
  for (int dt = 0; dt < 4; dt++) {
    uint2 ov = make_uint2(pkbf(o[dt][0] * rl, o[dt][1] * rl),
                          pkbf(o[dt][2] * rl, o[dt][3] * rl));
    *reinterpret_cast<uint2*>(&aout[orow + dt * 16 + grp * 4]) = ov;
  }
}

// ---------------- proj GEMM v2: 8-wave blocks, 32x32 per wave ----------------
// 512 threads; grid (mtile=x 32, ntile=y 16) = 512 blocks -> 2 blocks/CU = 16 waves/CU.
__global__ __launch_bounds__(512)
void gemm_proj(const ushort_t* __restrict__ A, const ushort_t* __restrict__ B,
               float* __restrict__ Cout, const float* __restrict__ bias) {
  const int K = 1024, N = 1024;
  __shared__ __align__(16) ushort_t smem[16384];   // 32KB: sA(16K)+sB(8K); sT aliases all
  ushort_t* sA = smem;
  ushort_t* sB = smem + 8192;
  const int m0 = blockIdx.x * 128, n0 = blockIdx.y * 64;
  const int tid = threadIdx.x;
  const int lane = tid & 63, w = tid >> 6;
  const int wm = (w >> 1) * 32, wn = (w & 1) * 32;
  const int grp = lane >> 4, l16 = lane & 15;
  const int r8 = lane >> 3;
  const int c8 = ((lane & 7) ^ r8) * 8;
  floatx4 acc[2][2] = {};
  for (int k0 = 0; k0 < K; k0 += 64) {
    __syncthreads();
#pragma unroll
    for (int i = 0; i < 2; i++) {
      const int j = w * 2 + i;
      gl2lds16(&A[(size_t)(m0 + j * 8 + r8) * K + k0 + c8], &sA[j * 512]);
    }
    gl2lds16(&B[(size_t)(n0 + w * 8 + r8) * K + k0 + c8], &sB[w * 512]);
    __syncthreads();
#pragma unroll
    for (int kk = 0; kk < 2; kk++) {
      bf16x8 af[2], bfr[2];
#pragma unroll
      for (int i = 0; i < 2; i++) {
        const int ra = wm + i * 16 + l16;
        af[i] = *reinterpret_cast<const bf16x8*>(
            &sA[ra * 64 + (((kk * 4 + grp) ^ (ra & 7)) << 3)]);
      }
#pragma unroll
      for (int j = 0; j < 2; j++) {
        const int rb = wn + j * 16 + l16;
        bfr[j] = *reinterpret_cast<const bf16x8*>(
            &sB[rb * 64 + (((kk * 4 + grp) ^ (rb & 7)) << 3)]);
      }
#pragma unroll
      for (int i = 0; i < 2; i++)
#pragma unroll
        for (int j = 0; j < 2; j++)
          acc[i][j] = __builtin_amdgcn_mfma_f32_16x16x32_bf16(af[i], bfr[j], acc[i][j], 0, 0, 0);
    }
  }
  __syncthreads();                 // K-loop LDS reads done before sT overwrites
  // phase A: bias + per-wave 32x32 fp32 tile (4KB at smem + w*4KB), swizzle by row&7
  float* sT = (float*)(smem + w * 2048);
  float bv[2];
#pragma unroll
  for (int j = 0; j < 2; j++) bv[j] = bias[n0 + wn + j * 16 + l16];
#pragma unroll
  for (int i = 0; i < 2; i++)
#pragma unroll
    for (int j = 0; j < 2; j++) {
      const int col = j * 16 + l16, c4 = col >> 2;
#pragma unroll
      for (int rr = 0; rr < 4; rr++) {
        const int row = i * 16 + grp * 4 + rr;
        sT[row * 32 + ((c4 ^ (row & 7)) << 2) + (col & 3)] = acc[i][j][rr] + bv[j];
      }
    }
  __builtin_amdgcn_s_waitcnt(0);   // per-wave tile: LDS writes before reads
  const int lr = lane >> 3, ch = lane & 7;
#pragma unroll
  for (int rg = 0; rg < 4; rg++) {
    const int row = rg * 8 + lr;
    float4 vvv = *(const float4*)&sT[row * 32 + ((ch ^ (row & 7)) << 2)];
    *reinterpret_cast<float4*>(&Cout[(size_t)(m0 + wm + row) * N + n0 + wn + ch * 4]) = vvv;
  }
}

extern "C" void kernel_launch(void* const* d_in, const int* in_sizes, int n_in,
                              void* d_out, int out_size, void* d_ws, size_t ws_size,
                              hipStream_t stream) {
  const float* x      = (const float*)d_in[0];   // [2,2048,1024]
  const float* pos    = (const float*)d_in[1];   // [2048,32]
  const float* qkv_w  = (const float*)d_in[2];   // [3072,1024]
  const float* q_nw   = (const float*)d_in[3];   // [64]
  const float* k_nw   = (const float*)d_in[4];   // [64]
  const float* proj_w = (const float*)d_in[5];   // [1024,1024]
  const float* proj_b = (const float*)d_in[6];   // [1024]
  float* out = (float*)d_out;                    // [2,2048,1024] fp32

  ushort_t* x_b     = (ushort_t*)d_ws;                         // 4096*1024
  ushort_t* qkvw_b  = x_b     + (size_t)4096 * 1024;           // 3072*1024
  ushort_t* projw_b = qkvw_b  + (size_t)3072 * 1024;           // 1024*1024
  ushort_t* q_r     = projw_b + (size_t)1024 * 1024;           // 32*2048*64
  ushort_t* k_r     = q_r     + (size_t)32 * 2048 * 64;
  ushort_t* v_t     = k_r     + (size_t)32 * 2048 * 64;
  ushort_t* a_out   = v_t     + (size_t)32 * 2048 * 64;        // 4096*1024
  float*    cs_tab  = (float*)(a_out + (size_t)4096 * 1024);   // 65536*2 fp32 (512KB)

  cast_all<<<8388608 / 4 / 256, 256, 0, stream>>>(x, qkv_w, proj_w, x_b, pos, cs_tab);

  gemm_qkv_fused<<<dim3(4096 / 128, 3072 / 128), 512, 0, stream>>>(
      x_b, qkvw_b, cs_tab, q_nw, k_nw, q_r, k_r, v_t);

  flash_attn<<<dim3(32, 2048 / 128), 512, 0, stream>>>(q_r, k_r, v_t, a_out);

  gemm_proj<<<dim3(4096 / 128, 1024 / 64), 512, 0, stream>>>(a_out, projw_b, out, proj_b);
}

// Round 14
// 179.967 us; speedup vs baseline: 1.0073x; 1.0073x over previous
//
#include <hip/hip_runtime.h>
#include <hip/hip_bf16.h>

typedef unsigned short ushort_t;
using floatx4 = __attribute__((__ext_vector_type__(4))) float;
using bf16x8  = __attribute__((__ext_vector_type__(8))) __bf16;
using ushort4v = __attribute__((__ext_vector_type__(4))) ushort_t;

// packed f32x2 -> bf16x2 (v_cvt_pk_bf16_f32); memcpy because __hip_bfloat162
// is not trivially copyable
__device__ __forceinline__ unsigned int pkbf(float a, float b) {
  __hip_bfloat162 h = __float22bfloat162_rn(make_float2(a, b));
  unsigned int u;
  __builtin_memcpy(&u, &h, 4);
  return u;
}

// async global->LDS, 16B per lane; lds dest is wave-uniform base (HW adds lane*16)
__device__ __forceinline__ void gl2lds16(const ushort_t* g, ushort_t* l) {
  __builtin_amdgcn_global_load_lds(
      (const __attribute__((address_space(1))) unsigned int*)g,
      (__attribute__((address_space(3))) unsigned int*)l, 16, 0, 0);
}

// ---------------- merged cast fp32 -> bf16 of x, qkv_w, proj_w + cos/sin table ----------------
__global__ void cast_all(const float* __restrict__ x, const float* __restrict__ qw,
                         const float* __restrict__ pw, ushort_t* __restrict__ ob,
                         const float* __restrict__ pos, float* __restrict__ cs) {
  const int T1 = 4096 * 1024, T2 = T1 + 3072 * 1024, T3 = T2 + 1024 * 1024;
  const int tid = blockIdx.x * blockDim.x + threadIdx.x;
  if (tid < 65536) {              // 2048 tokens x 32 angles
    const float a = pos[tid];
    cs[2 * tid]     = __cosf(a);
    cs[2 * tid + 1] = __sinf(a);
  }
  const int i = tid * 4;
  if (i < T3) {
    const float* src = (i < T1) ? (x + i) : (i < T2) ? (qw + (i - T1)) : (pw + (i - T2));
    float4 v = *reinterpret_cast<const float4*>(src);
    uint2 o = make_uint2(pkbf(v.x, v.y), pkbf(v.z, v.w));
    *reinterpret_cast<uint2*>(&ob[i]) = o;
  }
}

// ---------------- QKV GEMM v3: 8-wave blocks, 32x64 per wave + fused epilogue ----------------
// 512 threads, 8 waves: wave w owns m-rows (w>>1)*32.., n-cols (w&1)*64.. (one full head).
// grid (mtile=x 32, ntile=y 24): id%8 pins A-tiles per XCD. LDS 32KB swizzled; the
// per-wave 4KB epilogue tiles alias sA|sB after the K-loop.
__global__ __launch_bounds__(512)
void gemm_qkv_fused(const ushort_t* __restrict__ A, const ushort_t* __restrict__ B,
                    const float* __restrict__ cs,
                    const float* __restrict__ qnw, const float* __restrict__ knw,
                    ushort_t* __restrict__ qr, ushort_t* __restrict__ kr,
                    ushort_t* __restrict__ vt) {
  const int K = 1024;
  __shared__ __align__(16) ushort_t smem[16384];   // 32KB: sA(16K) | sB(16K), aliased by sE
  ushort_t* sA = smem;
  ushort_t* sB = smem + 8192;
  const int m0 = blockIdx.x * 128, n0 = blockIdx.y * 128;
  const int tid = threadIdx.x;
  const int lane = tid & 63, w = tid >> 6;          // w in [0,8)
  const int wm = (w >> 1) * 32;
  const int grp = lane >> 4, l16 = lane & 15;
  const int r8 = lane >> 3;
  const int c8 = ((lane & 7) ^ r8) * 8;
  floatx4 acc[2][4] = {};
  for (int k0 = 0; k0 < K; k0 += 64) {
    __syncthreads();
#pragma unroll
    for (int i = 0; i < 2; i++) {
      const int j = w * 2 + i;                      // chunk 0..15 (8 rows x 128B)
      gl2lds16(&A[(size_t)(m0 + j * 8 + r8) * K + k0 + c8], &sA[j * 512]);
      gl2lds16(&B[(size_t)(n0 + j * 8 + r8) * K + k0 + c8], &sB[j * 512]);
    }
    __syncthreads();
#pragma unroll
    for (int kk = 0; kk < 2; kk++) {
      bf16x8 af[2], bfr[4];
#pragma unroll
      for (int i = 0; i < 2; i++) {
        const int ra = wm + i * 16 + l16;
        af[i] = *reinterpret_cast<const bf16x8*>(
            &sA[ra * 64 + (((kk * 4 + grp) ^ (ra & 7)) << 3)]);
      }
#pragma unroll
      for (int j = 0; j < 4; j++) {
        const int rb = (w & 1) * 64 + j * 16 + l16;
        bfr[j] = *reinterpret_cast<const bf16x8*>(
            &sB[rb * 64 + (((kk * 4 + grp) ^ (rb & 7)) << 3)]);
      }
#pragma unroll
      for (int i = 0; i < 2; i++)
#pragma unroll
        for (int j = 0; j < 4; j++)
          acc[i][j] = __builtin_amdgcn_mfma_f32_16x16x32_bf16(af[i], bfr[j], acc[i][j], 0, 0, 0);
    }
  }
  __syncthreads();                 // all K-loop LDS reads done before epilogue overwrites
  // ---- fused epilogue: per-wave 4KB tile at smem + w*4KB ----
  ushort_t* sE = smem + w * 2048;
  const int region = n0 >> 10;                 // 0=q,1=k,2=v
  const int h = ((n0 & 1023) >> 6) + (w & 1);  // head this wave owns
  const int tbase = m0 + wm;                   // 32-aligned token base
  const int bb = tbase >> 11;
  const int q = lane & 7;
  const int lr = lane >> 3;

  if (region < 2) {
    float* sEf = (float*)sE;                   // 16 tokens x 64 dims fp32 (4KB)
    const float* nwp = (region == 0) ? qnw : knw;
    const float qmul = (region == 0) ? 0.125f * 1.44269504088896340736f : 1.0f;
    float wgt[8];
    *(float4*)&wgt[0] = *(const float4*)&nwp[q * 8];
    *(float4*)&wgt[4] = *(const float4*)&nwp[q * 8 + 4];
#pragma unroll
    for (int p = 0; p < 2; p++) {              // 2 passes x 16 tokens
      __builtin_amdgcn_s_waitcnt(0);
      // phase A: dump fp32 [t2][d], 16B-chunk XOR swizzle by t2
#pragma unroll
      for (int rr = 0; rr < 4; rr++) {
        const int t2 = grp * 4 + rr;
#pragma unroll
        for (int j = 0; j < 4; j++) {
          const int cd = (j * 4 + (l16 >> 2)) ^ t2;
          sEf[t2 * 64 + cd * 4 + (l16 & 3)] = acc[p][j][rr];
        }
      }
      __builtin_amdgcn_s_waitcnt(0);
      // phase B: 8 lanes per token; lane handles dims [8q, 8q+8)
#pragma unroll
      for (int tg = 0; tg < 2; tg++) {
        const int t2 = tg * 8 + lr;
        const int n = (tbase + p * 16 + t2) & 2047;
        float v0[8];
        const int ck1 = (2 * q) ^ t2, ck2 = (2 * q + 1) ^ t2;
        *(float4*)&v0[0] = *(const float4*)&sEf[t2 * 64 + ck1 * 4];
        *(float4*)&v0[4] = *(const float4*)&sEf[t2 * 64 + ck2 * 4];
        float ss = 0.f;
#pragma unroll
        for (int e = 0; e < 8; e++) ss += v0[e] * v0[e];
        ss += __shfl_xor(ss, 1); ss += __shfl_xor(ss, 2); ss += __shfl_xor(ss, 4);
        const float rn = rsqrtf(ss * (1.0f / 64.0f) + 1e-6f);
        float4 c01 = *(const float4*)&cs[(n * 32 + q * 4) * 2];
        float4 c23 = *(const float4*)&cs[(n * 32 + q * 4) * 2 + 4];
        float ccv[4] = {c01.x, c01.z, c23.x, c23.z};
        float snv[4] = {c01.y, c01.w, c23.y, c23.w};
        union { unsigned int u32[4]; uint4 v4; } ov;
#pragma unroll
        for (int pp = 0; pp < 4; pp++) {
          const float cc = ccv[pp], sn = snv[pp];
          const float xr = v0[2 * pp] * rn * wgt[2 * pp];
          const float xi = v0[2 * pp + 1] * rn * wgt[2 * pp + 1];
          ov.u32[pp] = pkbf((xr * cc - xi * sn) * qmul, (xr * sn + xi * cc) * qmul);
        }
        const size_t rowb = ((size_t)(bb * 16 + h) * 2048 + n) * 64;
        if (region == 0)
          *reinterpret_cast<uint4*>(&qr[rowb + q * 8]) = ov.v4;
        else
          *reinterpret_cast<uint4*>(&kr[rowb + (q ^ (n & 7)) * 8]) = ov.v4;
      }
    }
  } else {
    // v region: per-wave [d][32-token] bf16 tile (4KB), rr-quads as b64,
    // 8B-chunk swizzle by d&7. Wave covers half a 64-key window (contiguous
    // permuted half: token t2 -> lidx = grp*8 + i*4 + rr).
    const int nw_ = tbase & 2047;
    const int n64 = nw_ & ~63;
    const int hw = (nw_ >> 5) & 1;             // which half of the window
#pragma unroll
    for (int i = 0; i < 2; i++)
#pragma unroll
      for (int j = 0; j < 4; j++) {
        const int d = j * 16 + l16;
        const int ct = (grp * 2 + i) ^ (d & 7);
        uint2 pk = make_uint2(pkbf(acc[i][j][0], acc[i][j][1]),
                              pkbf(acc[i][j][2], acc[i][j][3]));
        *reinterpret_cast<uint2*>(&sE[d * 32 + ct * 4]) = pk;
      }
    __builtin_amdgcn_s_waitcnt(0);
    // phase B: lane -> (d = dd*16 + lane>>2, lc = lane&3): one 16B granule
    const int lc = lane & 3;
#pragma unroll
    for (int dd = 0; dd < 4; dd++) {
      const int d = dd * 16 + (lane >> 2);
      union { ushort4v hh[2]; uint4 v4; } ob;
      ob.hh[0] = *reinterpret_cast<const ushort4v*>(&sE[d * 32 + (((2 * lc) ^ (d & 7)) * 4)]);
      ob.hh[1] = *reinterpret_cast<const ushort4v*>(&sE[d * 32 + (((2 * lc + 1) ^ (d & 7)) * 4)]);
      *reinterpret_cast<uint4*>(
          &vt[((size_t)(bb * 16 + h) * 64 + d) * 2048 + n64 + (((hw * 4 + lc) ^ (d & 7)) * 8)]) = ob.v4;
    }
  }
}

// ---------------- Flash attention (R12): 8-wave blocks, 128-key tiles, ones-MFMA denom ----------
// grid (bh=x 32, qtile=y 16), block 512 = 8 waves x 16 q-rows. XCD-pinned bh.
// 16 iters (128 keys each) minimizes barrier+vmcnt-drain count; occupancy is
// work-limited at 16 waves/CU (4096 total waves), so smaller LDS buys nothing (R13 lesson).
// No running max: ||q||=||k||=8 after RMSNorm => |score*log2e*scale| <= 11.6, exp2-safe.
__global__ __launch_bounds__(512)
void flash_attn(const ushort_t* __restrict__ qr, const ushort_t* __restrict__ kr,
                const ushort_t* __restrict__ vt, ushort_t* __restrict__ aout) {
  const int bh = blockIdx.x;
  const int w = threadIdx.x >> 6, lane = threadIdx.x & 63;
  const int grp = lane >> 4, l16 = lane & 15;
  const int sw = l16 & 7;
  const int q0 = blockIdx.y * 128 + w * 16;   // 16 q-rows per wave
  const size_t hb = (size_t)bh * 2048 * 64;

  __shared__ ushort_t sK[2][128 * 64];   // [key][d-swizzled], 16KB each
  __shared__ ushort_t sV[2][64 * 128];   // [d][128-key window permuted+swizzled], 16KB each

  const ushort_t* qp = &qr[hb + (size_t)(q0 + l16) * 64 + grp * 8];
  const bf16x8 qa0 = *reinterpret_cast<const bf16x8*>(qp);
  const bf16x8 qa1 = *reinterpret_cast<const bf16x8*>(qp + 32);

  floatx4 o[4] = {};
  floatx4 ol = {};        // ones-row accumulator: every reg = Sigma p for this lane's q

  union { ushort_t u[8]; bf16x8 v; } onef;
#pragma unroll
  for (int e = 0; e < 8; e++) onef.u[e] = 0x3F80;   // bf16 1.0

  auto stage = [&](int buf, int k0) {
    const ushort_t* kg = &kr[hb + (size_t)k0 * 64];
#pragma unroll
    for (int i = 0; i < 2; i++) {
      const int j = w * 2 + i;               // K chunk: rows j*8..j*8+7 (1KB)
      gl2lds16(kg + j * 512 + lane * 8, &sK[buf][j * 512]);
    }
#pragma unroll
    for (int i = 0; i < 2; i++) {
      const int d = (w * 2 + i) * 4;         // V chunk: d-rows d..d+3 (1KB)
      gl2lds16(&vt[((size_t)bh * 64 + d + (lane >> 4)) * 2048 + k0 + (lane & 15) * 8],
               &sV[buf][d * 128]);
    }
  };

  stage(0, 0);
  const int g0 = (grp ^ sw) * 8;
  for (int it = 0; it < 16; it++) {
    const int cur = it & 1;
    __syncthreads();
    if (it + 1 < 16) stage(1 - cur, (it + 1) * 128);
#pragma unroll
    for (int hh = 0; hh < 2; hh++) {
      const ushort_t* kb = &sK[cur][hh * 64 * 64];
      const ushort_t* vb = &sV[cur][hh * 64];
      floatx4 s[4];
#pragma unroll
      for (int nt = 0; nt < 4; nt++) {
        const ushort_t* kp = kb + (nt * 16 + l16) * 64;
        bf16x8 kf0 = *reinterpret_cast<const bf16x8*>(kp + g0);
        bf16x8 kf1 = *reinterpret_cast<const bf16x8*>(kp + (g0 ^ 32));
        floatx4 acc = {};
        acc = __builtin_amdgcn_mfma_f32_16x16x32_bf16(kf0, qa0, acc, 0, 0, 0);
        acc = __builtin_amdgcn_mfma_f32_16x16x32_bf16(kf1, qa1, acc, 0, 0, 0);
        s[nt] = acc;
      }
      float p[4][4];
#pragma unroll
      for (int nt = 0; nt < 4; nt++)
#pragma unroll
        for (int r = 0; r < 4; r++)
          p[nt][r] = __builtin_amdgcn_exp2f(s[nt][r]);
      union { unsigned int u32[4]; bf16x8 v; } pf[2];
#pragma unroll
      for (int c = 0; c < 2; c++) {
        pf[c].u32[0] = pkbf(p[2 * c][0], p[2 * c][1]);
        pf[c].u32[1] = pkbf(p[2 * c][2], p[2 * c][3]);
        pf[c].u32[2] = pkbf(p[2 * c + 1][0], p[2 * c + 1][1]);
        pf[c].u32[3] = pkbf(p[2 * c + 1][2], p[2 * c + 1][3]);
      }
#pragma unroll
      for (int c = 0; c < 2; c++) {
        ol = __builtin_amdgcn_mfma_f32_16x16x32_bf16(onef.v, pf[c].v, ol, 0, 0, 0);
#pragma unroll
        for (int dt = 0; dt < 4; dt++) {
          const bf16x8 vv = *reinterpret_cast<const bf16x8*>(
              vb + (dt * 16 + l16) * 128 + (((c * 4 + grp) ^ sw) << 3));
          o[dt] = __builtin_amdgcn_mfma_f32_16x16x32_bf16(vv, pf[c].v, o[dt], 0, 0, 0);
        }
      }
    }
  }
  const int b = bh >> 4, h = bh & 15;
  const float rl = 1.0f / ol[0];
  const size_t orow = (size_t)(b * 2048 + q0 + l16) * 1024 + h * 64;
#pragma unroll
  for (int dt = 0; dt < 4; dt++) {
    uint2 ov = make_uint2(pkbf(o[dt][0] * rl, o[dt][1] * rl),
                          pkbf(o[dt][2] * rl, o[dt][3] * rl));
    *reinterpret_cast<uint2*>(&aout[orow + dt * 16 + grp * 4]) = ov;
  }
}

// ---------------- proj GEMM v2: 8-wave blocks, 32x32 per wave ----------------
// 512 threads; grid (mtile=x 32, ntile=y 16) = 512 blocks -> 2 blocks/CU = 16 waves/CU.
__global__ __launch_bounds__(512)
void gemm_proj(const ushort_t* __restrict__ A, const ushort_t* __restrict__ B,
               float* __restrict__ Cout, const float* __restrict__ bias) {
  const int K = 1024, N = 1024;
  __shared__ __align__(16) ushort_t smem[16384];   // 32KB: sA(16K)+sB(8K); sT aliases all
  ushort_t* sA = smem;
  ushort_t* sB = smem + 8192;
  const int m0 = blockIdx.x * 128, n0 = blockIdx.y * 64;
  const int tid = threadIdx.x;
  const int lane = tid & 63, w = tid >> 6;
  const int wm = (w >> 1) * 32, wn = (w & 1) * 32;
  const int grp = lane >> 4, l16 = lane & 15;
  const int r8 = lane >> 3;
  const int c8 = ((lane & 7) ^ r8) * 8;
  floatx4 acc[2][2] = {};
  for (int k0 = 0; k0 < K; k0 += 64) {
    __syncthreads();
#pragma unroll
    for (int i = 0; i < 2; i++) {
      const int j = w * 2 + i;
      gl2lds16(&A[(size_t)(m0 + j * 8 + r8) * K + k0 + c8], &sA[j * 512]);
    }
    gl2lds16(&B[(size_t)(n0 + w * 8 + r8) * K + k0 + c8], &sB[w * 512]);
    __syncthreads();
#pragma unroll
    for (int kk = 0; kk < 2; kk++) {
      bf16x8 af[2], bfr[2];
#pragma unroll
      for (int i = 0; i < 2; i++) {
        const int ra = wm + i * 16 + l16;
        af[i] = *reinterpret_cast<const bf16x8*>(
            &sA[ra * 64 + (((kk * 4 + grp) ^ (ra & 7)) << 3)]);
      }
#pragma unroll
      for (int j = 0; j < 2; j++) {
        const int rb = wn + j * 16 + l16;
        bfr[j] = *reinterpret_cast<const bf16x8*>(
            &sB[rb * 64 + (((kk * 4 + grp) ^ (rb & 7)) << 3)]);
      }
#pragma unroll
      for (int i = 0; i < 2; i++)
#pragma unroll
        for (int j = 0; j < 2; j++)
          acc[i][j] = __builtin_amdgcn_mfma_f32_16x16x32_bf16(af[i], bfr[j], acc[i][j], 0, 0, 0);
    }
  }
  __syncthreads();                 // K-loop LDS reads done before sT overwrites
  // phase A: bias + per-wave 32x32 fp32 tile (4KB at smem + w*4KB), swizzle by row&7
  float* sT = (float*)(smem + w * 2048);
  float bv[2];
#pragma unroll
  for (int j = 0; j < 2; j++) bv[j] = bias[n0 + wn + j * 16 + l16];
#pragma unroll
  for (int i = 0; i < 2; i++)
#pragma unroll
    for (int j = 0; j < 2; j++) {
      const int col = j * 16 + l16, c4 = col >> 2;
#pragma unroll
      for (int rr = 0; rr < 4; rr++) {
        const int row = i * 16 + grp * 4 + rr;
        sT[row * 32 + ((c4 ^ (row & 7)) << 2) + (col & 3)] = acc[i][j][rr] + bv[j];
      }
    }
  __builtin_amdgcn_s_waitcnt(0);   // per-wave tile: LDS writes before reads
  const int lr = lane >> 3, ch = lane & 7;
#pragma unroll
  for (int rg = 0; rg < 4; rg++) {
    const int row = rg * 8 + lr;
    float4 vvv = *(const float4*)&sT[row * 32 + ((ch ^ (row & 7)) << 2)];
    *reinterpret_cast<float4*>(&Cout[(size_t)(m0 + wm + row) * N + n0 + wn + ch * 4]) = vvv;
  }
}

extern "C" void kernel_launch(void* const* d_in, const int* in_sizes, int n_in,
                              void* d_out, int out_size, void* d_ws, size_t ws_size,
                              hipStream_t stream) {
  const float* x      = (const float*)d_in[0];   // [2,2048,1024]
  const float* pos    = (const float*)d_in[1];   // [2048,32]
  const float* qkv_w  = (const float*)d_in[2];   // [3072,1024]
  const float* q_nw   = (const float*)d_in[3];   // [64]
  const float* k_nw   = (const float*)d_in[4];   // [64]
  const float* proj_w = (const float*)d_in[5];   // [1024,1024]
  const float* proj_b = (const float*)d_in[6];   // [1024]
  float* out = (float*)d_out;                    // [2,2048,1024] fp32

  ushort_t* x_b     = (ushort_t*)d_ws;                         // 4096*1024
  ushort_t* qkvw_b  = x_b     + (size_t)4096 * 1024;           // 3072*1024
  ushort_t* projw_b = qkvw_b  + (size_t)3072 * 1024;           // 1024*1024
  ushort_t* q_r     = projw_b + (size_t)1024 * 1024;           // 32*2048*64
  ushort_t* k_r     = q_r     + (size_t)32 * 2048 * 64;
  ushort_t* v_t     = k_r     + (size_t)32 * 2048 * 64;
  ushort_t* a_out   = v_t     + (size_t)32 * 2048 * 64;        // 4096*1024
  float*    cs_tab  = (float*)(a_out + (size_t)4096 * 1024);   // 65536*2 fp32 (512KB)

  cast_all<<<8388608 / 4 / 256, 256, 0, stream>>>(x, qkv_w, proj_w, x_b, pos, cs_tab);

  gemm_qkv_fused<<<dim3(4096 / 128, 3072 / 128), 512, 0, stream>>>(
      x_b, qkvw_b, cs_tab, q_nw, k_nw, q_r, k_r, v_t);

  flash_attn<<<dim3(32, 2048 / 128), 512, 0, stream>>>(q_r, k_r, v_t, a_out);

  gemm_proj<<<dim3(4096 / 128, 1024 / 64), 512, 0, stream>>>(a_out, projw_b, out, proj_b);
}